// Round 6
// baseline (4322.226 us; speedup 1.0000x reference)
//
#include <hip/hip_runtime.h>
#include <math.h>

#define BATCH 256
#define TT    127      // T-1 time steps
#define DD    512
#define HH    512
#define GG    2048     // 4*H
#define NWG   256
#define NTHR  256
#define OUT0_ELEMS ((size_t)BATCH * TT * DD)   // 16,646,144
#define BARSLOT   2048                          // bytes between barrier slots

typedef __attribute__((ext_vector_type(8))) short  short8;
typedef __attribute__((ext_vector_type(4))) float  floatx4;
typedef __attribute__((ext_vector_type(4))) unsigned int uintx4;

__device__ __forceinline__ float bf2f(unsigned short u) {
    unsigned int x = ((unsigned int)u) << 16;
    return __builtin_bit_cast(float, x);
}
__device__ __forceinline__ unsigned short f2bf(float f) {
    unsigned int x = __builtin_bit_cast(unsigned int, f);
    unsigned int lsb = (x >> 16) & 1u;
    x += 0x7fffu + lsb;                 // round-to-nearest-even
    return (unsigned short)(x >> 16);
}

// Detect whether a buffer of ~N(0,1) values is stored as f32 or bf16.
__device__ __forceinline__ int detect_is_f32(const unsigned short* p) {
    int cnt = 0;
    for (int i = 0; i < 64; ++i) {
        int e = (p[2 * i] >> 7) & 0xFF;
        cnt += (e >= 112 && e <= 133) ? 1 : 0;
    }
    return cnt < 32;
}

// A-fragment load: 8 contiguous K elements, bf16 direct or f32->bf16.
__device__ __forceinline__ short8 load_a8(const void* base, size_t off, int f32m) {
    if (!f32m) return *(const short8*)((const unsigned short*)base + off);
    const float* fp = (const float*)base + off;
    short8 r;
#pragma unroll
    for (int j = 0; j < 8; ++j) r[j] = (short)f2bf(fp[j]);
    return r;
}

// Coherent 16B load: ONE global_load_dwordx4 with sc0+sc1 (bypass L1+L2,
// served at the LLC). UNTRACKED by compiler waitcnt: caller must drain
// vmcnt(0) before consuming results.
__device__ __forceinline__ short8 load_h16(const unsigned short* p) {
    uintx4 r;
    asm volatile("global_load_dwordx4 %0, %1, off sc0 sc1"
                 : "=v"(r) : "v"(p));
    return __builtin_bit_cast(short8, r);
}

// ---------------------------------------------------------------------------
// Kernel 0: detect dtype; publish flag; bsum = b_ih + b_hh (f32);
// if f32 world, convert W_ih/W_hh to bf16 in ws.
// ---------------------------------------------------------------------------
__global__ __launch_bounds__(256) void prep_kernel(
    const void* __restrict__ W_ih, const void* __restrict__ W_hh,
    const void* __restrict__ b_ih, const void* __restrict__ b_hh,
    const unsigned short* __restrict__ x_u,
    unsigned short* __restrict__ wih_bf, unsigned short* __restrict__ whh_bf,
    float* __restrict__ bsum, int* __restrict__ flag_ws)
{
    __shared__ int sflag;
    if (threadIdx.x == 0) sflag = detect_is_f32(x_u);
    __syncthreads();
    const int f32m = sflag;
    const int gid = blockIdx.x * 256 + threadIdx.x;
    const int gsz = gridDim.x * 256;
    if (gid == 0) *flag_ws = f32m;

    for (int i = gid; i < 3 * GG; i += gsz) {
        float bi = f32m ? ((const float*)b_ih)[i] : bf2f(((const unsigned short*)b_ih)[i]);
        float bh = f32m ? ((const float*)b_hh)[i] : bf2f(((const unsigned short*)b_hh)[i]);
        bsum[i] = bi + bh;
    }
    if (f32m) {
        const float* wi = (const float*)W_ih;
        const float* wh = (const float*)W_hh;
        const int n = 3 * GG * DD;
        for (int i = gid; i < n; i += gsz) {
            wih_bf[i] = f2bf(wi[i]);
            whh_bf[i] = f2bf(wh[i]);
        }
    }
}

// ---------------------------------------------------------------------------
// Kernel 1: time-invariant input attention (h/c/bias terms cancel in
// softmax over d). out0[b,t,d] = softmax_d(sum_t x*w)[b,d] * x[b,t,d].
// ---------------------------------------------------------------------------
__global__ __launch_bounds__(512) void attn_kernel(
    const void* __restrict__ xv,       // [B][TT][DD]
    const void* __restrict__ attn_wv,  // [2H+TT]
    void* __restrict__ outv,           // output 0 region
    const int* __restrict__ flag_ws)
{
    __shared__ float red[512];
    __shared__ float wx[TT];
    __shared__ int sflag;
    const int b = blockIdx.x;
    const int d = threadIdx.x;          // 0..511
    if (d == 0) sflag = *flag_ws;
    __syncthreads();
    const int f32m = sflag;

    if (d < TT)
        wx[d] = f32m ? ((const float*)attn_wv)[2 * HH + d]
                     : bf2f(((const unsigned short*)attn_wv)[2 * HH + d]);
    __syncthreads();

    const size_t xb = (size_t)b * TT * DD;
    float s = 0.f;
    for (int t = 0; t < TT; ++t) {
        size_t ix = xb + (size_t)t * DD + d;
        float xval = f32m ? ((const float*)xv)[ix] : bf2f(((const unsigned short*)xv)[ix]);
        s += xval * wx[t];
    }

    red[d] = s; __syncthreads();
    for (int off = 256; off > 0; off >>= 1) {
        if (d < off) red[d] = fmaxf(red[d], red[d + off]);
        __syncthreads();
    }
    const float m = red[0]; __syncthreads();
    const float e = expf(s - m);
    red[d] = e; __syncthreads();
    for (int off = 256; off > 0; off >>= 1) {
        if (d < off) red[d] += red[d + off];
        __syncthreads();
    }
    const float a = e / red[0];

    for (int t = 0; t < TT; ++t) {
        size_t ix = xb + (size_t)t * DD + d;
        float xval = f32m ? ((const float*)xv)[ix] : bf2f(((const unsigned short*)xv)[ix]);
        float v = a * xval;
        if (f32m) ((float*)outv)[ix] = v;
        else      ((unsigned short*)outv)[ix] = f2bf(v);
    }
}

// ---------------------------------------------------------------------------
// Kernel 2: persistent 3-layer LSTM wavefront.
// Coherence design (proven R0-R4): h_ws written via agent-scope relaxed
// atomic stores (sc1, LLC write-through), read via global_load_dwordx4
// sc0 sc1, deduped to 3 slices / 24 loads per wave per tick;
// writeback-free arrival; SPSC group barriers (R4).
//
// NEW this round: RUNTIME XCD ROLE SELF-ASSIGNMENT.
//   The design requires each XCD's 32 blocks to cover only 4 hid slices
//   so the 1.5MB weight slice set is L2-resident; it assumed xcd=blk&7.
//   If the true workgroup->XCD mapping differs, unique weights per XCD
//   approach 12.6MB >> 4MB L2 -> the 12.3MB/XCD/tick weight stream
//   re-fetches from LLC every tick (~10-25us/tick), INVISIBLE in
//   FETCH_SIZE (HBM-only counter) -- matching the ~25us/tick residue
//   that survived every sync change (R0/R2/R4 nulls).
//   Fix: each block publishes s_getreg(HW_REG_XCC_ID); after a one-time
//   pre-barrier all blocks deterministically derive (hi,bi) from their
//   PHYSICAL XCD class and rank within it: hi = 4*xcc + (rank&3),
//   bi = rank>>2. Guarantees 4-slices-per-XCD under any mapping.
//   If classes are not exactly 8x32 (or s_getreg is garbage), ALL
//   blocks uniformly fall back to the blk-derived mapping. If the HW
//   mapping IS blk&7, the new roles are BIT-IDENTICAL to the old ones
//   (clean null). Correctness never depends on xcc values: any
//   balanced class partition yields a permutation of the 256 roles.
// ---------------------------------------------------------------------------
__global__ __launch_bounds__(256, 1) void lstm_kernel(
    void* __restrict__ outv,                  // d_out: read out0, write out1
    const unsigned short* __restrict__ W_ih_o,
    const unsigned short* __restrict__ W_hh_o,
    const unsigned short* __restrict__ wih_bf,
    const unsigned short* __restrict__ whh_bf,
    const float* __restrict__ bsum,           // [3][GG]
    unsigned short* __restrict__ h_ws,        // [3][2][B][HH] bf16 parity dbuf
    unsigned* __restrict__ bar,               // 512 slots x 2KB (arr, wake)
    unsigned* __restrict__ xmap,              // [NWG] xcc publish slots
    const int* __restrict__ flag_ws)
{
    __shared__ float g_lds[16 * 16 * 33];     // [(q*4+g)*16+hid]*33 + batch
    __shared__ unsigned x_lds[NWG];
    __shared__ int sflag;
    __shared__ int s_dead;
    __shared__ int s_role;

    const int tid = threadIdx.x;
    const int blk = blockIdx.x;
    if (tid == 0) { sflag = *flag_ws; s_dead = 0; }
    __syncthreads();
    const int f32m = sflag;

    // ---------------- one-time XCD role discovery ----------------
    if (tid == 0) {
        unsigned xcc;
        asm volatile("s_getreg_b32 %0, hwreg(HW_REG_XCC_ID)" : "=s"(xcc));
        __hip_atomic_store(&xmap[blk], (xcc & 7u) | 0x100u,
                           __ATOMIC_RELAXED, __HIP_MEMORY_SCOPE_AGENT);
    }
    {
        // pre-barrier: thread t polls block t's publish slot (load-only)
        int spins = 0; unsigned v = 0;
        for (;;) {
            v = __hip_atomic_load(&xmap[tid], __ATOMIC_RELAXED,
                                  __HIP_MEMORY_SCOPE_AGENT);
            if (v & 0x100u) break;
            __builtin_amdgcn_s_sleep(2);
            if (++spins > 5000000) break;
        }
        x_lds[tid] = v & 7u;
    }
    __syncthreads();
    if (tid == 0) {
        int cnt[8] = {0, 0, 0, 0, 0, 0, 0, 0};
        const int myc = (int)x_lds[blk];
        int rank = 0;
        for (int j = 0; j < NWG; ++j) {
            const int c = (int)x_lds[j];
            if (j < blk && c == myc) ++rank;
            cnt[c]++;
        }
        int balanced = 1;
        for (int c = 0; c < 8; ++c) balanced &= (cnt[c] == 32);
        int hi_l, bi_l;
        if (balanced) { hi_l = myc * 4 + (rank & 3); bi_l = rank >> 2; }
        else { hi_l = (blk & 7) * 4 + ((blk >> 3) & 3); bi_l = blk >> 5; }
        s_role = (hi_l << 8) | bi_l;
    }
    __syncthreads();
    const int hi = s_role >> 8;               // hidden slice 0..31
    const int bi = s_role & 255;              // batch tile 0..7

    const unsigned short* WiB = f32m ? wih_bf : W_ih_o;
    const unsigned short* WhB = f32m ? whh_bf : W_hh_o;

    const int lane   = tid & 63;
    const int wv     = tid >> 6;              // wave id 0..3 = K-quarter
    const int m_lane = lane & 15;
    const int kq     = lane >> 4;

    const int hid0 = hi * 16;
    const int b0   = bi * 32;
    const int leader = (hi == 0);             // one leader per group

    // SPSC barrier slots (2KB apart; 1 writer + 1 reader each)
    char* barc = (char*)bar;
    unsigned* arr_my  = (unsigned*)(barc + (size_t)(bi * 32 + hi) * BARSLOT);
    unsigned* wake_my = (unsigned*)(barc + (size_t)(256 + bi * 32 + hi) * BARSLOT);
    // leader wave0: lane j polls arrival slot j (lanes>=32 mirror slot 31)
    unsigned* poll_slot = (unsigned*)(barc +
        (size_t)(bi * 32 + (tid < 32 ? tid : 31)) * BARSLOT);
    unsigned* wake_slot = (unsigned*)(barc +
        (size_t)(256 + bi * 32 + (tid < 32 ? tid : 31)) * BARSLOT);

    // epilogue ownership: thread -> (batch bl, hid pair hp)
    const int ep_bl = tid >> 3;               // 0..31
    const int ep_hp = tid & 7;                // hid pair, hids {2hp, 2hp+1}

    float c_reg[3][2];
#pragma unroll
    for (int l = 0; l < 3; ++l) { c_reg[l][0] = 0.f; c_reg[l][1] = 0.f; }

    for (int k = 0; k < TT + 2; ++k) {
        // ---- tick-start burst: 24 coherent 16B loads (3 unique slices) ----
        // pfb[j] = h_j[k-1-j] (parity (k-j-1)&1). Serves BOTH layer j's
        // hprev and layer j+1's hsrc. Load iff 0 <= k-j <= TT. (-1)&1==1:
        // the t=-1 read hits the memset-zeroed parity-1 buffer.
        short8 pfb[3][4][2];
#pragma unroll
        for (int j = 0; j < 3; ++j) {
            const int kj = k - j;
            if (kj < 0 || kj > TT) continue;  // uniform across wgs & threads
            const unsigned short* hb =
                h_ws + ((size_t)j * 2 + ((kj - 1) & 1)) * BATCH * HH;
#pragma unroll
            for (int kk = 0; kk < 4; ++kk) {
                const int k0 = (wv * 4 + kk) * 32 + kq * 8;
                pfb[j][kk][0] = load_h16(hb + (size_t)(b0 + m_lane) * HH + k0);
                pfb[j][kk][1] = load_h16(hb + (size_t)(b0 + 16 + m_lane) * HH + k0);
            }
        }
        // drain the untracked asm loads ONCE; fence the scheduler so no
        // consumer is hoisted above the wait (rule 18).
        asm volatile("s_waitcnt vmcnt(0)" ::: "memory");
        __builtin_amdgcn_sched_barrier(0);

        // --------------------------- compute ----------------------------
#pragma unroll
        for (int l = 0; l < 3; ++l) {
            const int t = k - l;
            if (t < 0 || t >= TT) continue;   // uniform across wgs & threads

            const unsigned short* Wi = WiB + (size_t)l * GG * DD;
            const unsigned short* Wh = WhB + (size_t)l * GG * DD;

            floatx4 acc[2][4];
#pragma unroll
            for (int mt = 0; mt < 2; ++mt)
#pragma unroll
                for (int g = 0; g < 4; ++g) {
                    floatx4 z = {0.f, 0.f, 0.f, 0.f};
                    acc[mt][g] = z;
                }

#pragma unroll
            for (int kk = 0; kk < 4; ++kk) {
                const int k0 = (wv * 4 + kk) * 32 + kq * 8;
                short8 a0, a1;
                if (l == 0) {
                    a0 = load_a8(outv, ((size_t)(b0 + m_lane) * TT + t) * DD + k0, f32m);
                    a1 = load_a8(outv, ((size_t)(b0 + 16 + m_lane) * TT + t) * DD + k0, f32m);
                } else {
                    a0 = pfb[l - 1][kk][0];   // hsrc == hprev of layer l-1
                    a1 = pfb[l - 1][kk][1];
                }
#pragma unroll
                for (int g = 0; g < 4; ++g) {
                    short8 bfr = *(const short8*)(Wi + (size_t)(g * HH + hid0 + m_lane) * DD + k0);
                    acc[0][g] = __builtin_amdgcn_mfma_f32_16x16x32_bf16(a0, bfr, acc[0][g], 0, 0, 0);
                    acc[1][g] = __builtin_amdgcn_mfma_f32_16x16x32_bf16(a1, bfr, acc[1][g], 0, 0, 0);
                }
                short8 h0f = pfb[l][kk][0];
                short8 h1f = pfb[l][kk][1];
#pragma unroll
                for (int g = 0; g < 4; ++g) {
                    short8 bfr = *(const short8*)(Wh + (size_t)(g * HH + hid0 + m_lane) * DD + k0);
                    acc[0][g] = __builtin_amdgcn_mfma_f32_16x16x32_bf16(h0f, bfr, acc[0][g], 0, 0, 0);
                    acc[1][g] = __builtin_amdgcn_mfma_f32_16x16x32_bf16(h1f, bfr, acc[1][g], 0, 0, 0);
                }
            }

            // combine 4 waves' K-partials in LDS
            __syncthreads();
#pragma unroll
            for (int mt = 0; mt < 2; ++mt)
#pragma unroll
                for (int g = 0; g < 4; ++g)
#pragma unroll
                    for (int r = 0; r < 4; ++r)
                        g_lds[((wv * 4 + g) * 16 + m_lane) * 33 + mt * 16 + kq * 4 + r]
                            = acc[mt][g][r];
            __syncthreads();

            // epilogue: each thread owns (bl, hid-pair) -> packed u32 h-store
            {
                float hout[2];
#pragma unroll
                for (int dlt = 0; dlt < 2; ++dlt) {
                    const int hid = 2 * ep_hp + dlt;
                    float gv[4];
#pragma unroll
                    for (int g = 0; g < 4; ++g) {
                        float sum = 0.f;
#pragma unroll
                        for (int q = 0; q < 4; ++q)
                            sum += g_lds[((q * 4 + g) * 16 + hid) * 33 + ep_bl];
                        sum += bsum[l * GG + g * HH + hid0 + hid];
                        gv[g] = sum;
                    }
                    const float ig = 1.f / (1.f + expf(-gv[0]));
                    const float fg = 1.f / (1.f + expf(-gv[1]));
                    const float gg = tanhf(gv[2]);
                    const float og = 1.f / (1.f + expf(-gv[3]));
                    const float cnew = fg * c_reg[l][dlt] + ig * gg;
                    c_reg[l][dlt] = cnew;
                    hout[dlt] = og * tanhf(cnew);
                }
                const int bgl  = b0 + ep_bl;
                const int hidg = hid0 + 2 * ep_hp;
                const unsigned hpk = (unsigned)f2bf(hout[0])
                                   | ((unsigned)f2bf(hout[1]) << 16);
                __hip_atomic_store(
                    (unsigned*)(h_ws + (((size_t)l * 2 + (t & 1)) * BATCH + bgl) * HH + hidg),
                    hpk, __ATOMIC_RELAXED, __HIP_MEMORY_SCOPE_AGENT);
                if (l == 2) {
                    const size_t ox = OUT0_ELEMS + ((size_t)bgl * TT + t) * HH + hidg;
                    if (f32m) {
                        ((float*)outv)[ox]     = hout[0];
                        ((float*)outv)[ox + 1] = hout[1];
                    } else {
                        *(unsigned*)((unsigned short*)outv + ox) = hpk;
                    }
                }
            }
        }

        if (k < TT + 1) {
            // __syncthreads drains every wave's vmcnt (compiler emits
            // s_waitcnt vmcnt(0) lgkmcnt(0) before s_barrier) -> all h
            // stores of this block are LLC-visible before the arrival.
            __syncthreads();
            if (!s_dead) {
                if (tid == 0) {
                    asm volatile("s_waitcnt vmcnt(0)" ::: "memory");
                    __hip_atomic_store(arr_my, (unsigned)(k + 1),
                                       __ATOMIC_RELAXED, __HIP_MEMORY_SCOPE_AGENT);
                }
                if (leader) {
                    if (tid < 64) {
                        // lane-parallel poll of the 32 arrival slots:
                        // one LLC round-trip per poll round.
                        int spins = 0;
                        for (;;) {
                            unsigned v = __hip_atomic_load(poll_slot,
                                __ATOMIC_RELAXED, __HIP_MEMORY_SCOPE_AGENT);
                            if (__all(v > (unsigned)k)) break;
                            __builtin_amdgcn_s_sleep(4);
                            if (++spins > 2000000) {
                                if (tid == 0) s_dead = 1;
                                break;
                            }
                        }
                        if (tid < 32)
                            __hip_atomic_store(wake_slot, (unsigned)(k + 1),
                                __ATOMIC_RELAXED, __HIP_MEMORY_SCOPE_AGENT);
                    }
                } else if (tid == 0) {
                    int spins = 0;
                    while (__hip_atomic_load(wake_my, __ATOMIC_RELAXED,
                                             __HIP_MEMORY_SCOPE_AGENT)
                           <= (unsigned)k) {
                        __builtin_amdgcn_s_sleep(4);
                        if (++spins > 2000000) { s_dead = 1; break; }
                    }
                }
            }
            __syncthreads();
        }
    }
}

// ---------------------------------------------------------------------------
// workspace layout (bytes)
// ---------------------------------------------------------------------------
#define WIH_OFF  ((size_t)0)
#define WIH_SZ   ((size_t)3 * GG * DD * 2)          // 6,291,456
#define WHH_OFF  (WIH_OFF + WIH_SZ)
#define WHH_SZ   WIH_SZ
#define BSUM_OFF (WHH_OFF + WHH_SZ)
#define BSUM_SZ  ((size_t)3 * GG * 4)               // 24,576
#define H_OFF    (BSUM_OFF + BSUM_SZ)
#define H_SZ     ((size_t)3 * 2 * BATCH * HH * 2)   // 1,572,864
#define BAR_OFF  (H_OFF + H_SZ)                     // 512 slots x 2KB
#define BAR_SZ   ((size_t)512 * BARSLOT)            // 1,048,576
#define FLAG_OFF (BAR_OFF + BAR_SZ)
#define XMAP_OFF (FLAG_OFF + 256)
#define XMAP_SZ  ((size_t)NWG * 4 + 256)
#define WS_NEED  (XMAP_OFF + XMAP_SZ)               // ~15.3 MB

extern "C" void kernel_launch(void* const* d_in, const int* in_sizes, int n_in,
                              void* d_out, int out_size, void* d_ws, size_t ws_size,
                              hipStream_t stream) {
    (void)in_sizes; (void)n_in; (void)out_size;

    const void* x      = d_in[0];
    const void* W_ih   = d_in[1];
    const void* W_hh   = d_in[2];
    const void* b_ih   = d_in[3];
    const void* b_hh   = d_in[4];
    const void* attn_w = d_in[5];
    // d_in[6] (attn_b) cancels in the softmax — unused.

    char* ws = (char*)d_ws;
    unsigned short* wih_bf = (unsigned short*)(ws + WIH_OFF);
    unsigned short* whh_bf = (unsigned short*)(ws + WHH_OFF);
    float*          bsum   = (float*)(ws + BSUM_OFF);
    unsigned short* h_ws   = (unsigned short*)(ws + H_OFF);
    unsigned*       bar    = (unsigned*)(ws + BAR_OFF);
    int*            flagp  = (int*)(ws + FLAG_OFF);
    unsigned*       xmap   = (unsigned*)(ws + XMAP_OFF);

    if (ws_size < WS_NEED) return;

    // zero h (both parities) + barrier slots + flag + xmap every call
    hipMemsetAsync(ws + H_OFF, 0, WS_NEED - H_OFF, stream);

    prep_kernel<<<dim3(1024), dim3(256), 0, stream>>>(
        W_ih, W_hh, b_ih, b_hh, (const unsigned short*)x,
        wih_bf, whh_bf, bsum, flagp);

    attn_kernel<<<dim3(BATCH), dim3(512), 0, stream>>>(x, attn_w, d_out, flagp);

    lstm_kernel<<<dim3(NWG), dim3(NTHR), 0, stream>>>(
        d_out, (const unsigned short*)W_ih, (const unsigned short*)W_hh,
        wih_bf, whh_bf, bsum, h_ws, bar, xmap, flagp);
}

// Round 7
// 4029.203 us; speedup vs baseline: 1.0727x; 1.0727x over previous
//
#include <hip/hip_runtime.h>
#include <math.h>

#define BATCH 256
#define TT    127      // T-1 time steps
#define DD    512
#define HH    512
#define GG    2048     // 4*H
#define NWG   256
#define NTHR  256
#define OUT0_ELEMS ((size_t)BATCH * TT * DD)   // 16,646,144
#define BARSLOT   2048                          // bytes between barrier slots

typedef __attribute__((ext_vector_type(8))) short  short8;
typedef __attribute__((ext_vector_type(4))) float  floatx4;
typedef __attribute__((ext_vector_type(4))) unsigned int uintx4;

__device__ __forceinline__ float bf2f(unsigned short u) {
    unsigned int x = ((unsigned int)u) << 16;
    return __builtin_bit_cast(float, x);
}
__device__ __forceinline__ unsigned short f2bf(float f) {
    unsigned int x = __builtin_bit_cast(unsigned int, f);
    unsigned int lsb = (x >> 16) & 1u;
    x += 0x7fffu + lsb;                 // round-to-nearest-even
    return (unsigned short)(x >> 16);
}

// Detect whether a buffer of ~N(0,1) values is stored as f32 or bf16.
__device__ __forceinline__ int detect_is_f32(const unsigned short* p) {
    int cnt = 0;
    for (int i = 0; i < 64; ++i) {
        int e = (p[2 * i] >> 7) & 0xFF;
        cnt += (e >= 112 && e <= 133) ? 1 : 0;
    }
    return cnt < 32;
}

// Coherent 16B load: ONE global_load_dwordx4 with sc0+sc1 (bypass L1+L2,
// served at the LLC). UNTRACKED by compiler waitcnt: caller must drain
// vmcnt(0) before consuming results.
__device__ __forceinline__ short8 load_h16(const unsigned short* p) {
    uintx4 r;
    asm volatile("global_load_dwordx4 %0, %1, off sc0 sc1"
                 : "=v"(r) : "v"(p));
    return __builtin_bit_cast(short8, r);
}

// ---------------------------------------------------------------------------
// Kernel 0: detect dtype; publish flag; bsum = b_ih + b_hh (f32);
// if f32 world, convert W_ih/W_hh to bf16 in ws.
// ---------------------------------------------------------------------------
__global__ __launch_bounds__(256) void prep_kernel(
    const void* __restrict__ W_ih, const void* __restrict__ W_hh,
    const void* __restrict__ b_ih, const void* __restrict__ b_hh,
    const unsigned short* __restrict__ x_u,
    unsigned short* __restrict__ wih_bf, unsigned short* __restrict__ whh_bf,
    float* __restrict__ bsum, int* __restrict__ flag_ws)
{
    __shared__ int sflag;
    if (threadIdx.x == 0) sflag = detect_is_f32(x_u);
    __syncthreads();
    const int f32m = sflag;
    const int gid = blockIdx.x * 256 + threadIdx.x;
    const int gsz = gridDim.x * 256;
    if (gid == 0) *flag_ws = f32m;

    for (int i = gid; i < 3 * GG; i += gsz) {
        float bi = f32m ? ((const float*)b_ih)[i] : bf2f(((const unsigned short*)b_ih)[i]);
        float bh = f32m ? ((const float*)b_hh)[i] : bf2f(((const unsigned short*)b_hh)[i]);
        bsum[i] = bi + bh;
    }
    if (f32m) {
        const float* wi = (const float*)W_ih;
        const float* wh = (const float*)W_hh;
        const int n = 3 * GG * DD;
        for (int i = gid; i < n; i += gsz) {
            wih_bf[i] = f2bf(wi[i]);
            whh_bf[i] = f2bf(wh[i]);
        }
    }
}

// ---------------------------------------------------------------------------
// Kernel 1: time-invariant input attention (h/c/bias terms cancel in
// softmax over d). out0[b,t,d] = softmax_d(sum_t x*w)[b,d] * x[b,t,d].
// NEW: also writes a bf16 copy x_bf[b][t][d] for the LSTM's A operand
// (kills the 128-scalar-loads-per-wave f32 A path -- see lstm header).
// ---------------------------------------------------------------------------
__global__ __launch_bounds__(512) void attn_kernel(
    const void* __restrict__ xv,       // [B][TT][DD]
    const void* __restrict__ attn_wv,  // [2H+TT]
    void* __restrict__ outv,           // output 0 region
    unsigned short* __restrict__ x_bf, // [B][TT][DD] bf16 copy of out0
    const int* __restrict__ flag_ws)
{
    __shared__ float red[512];
    __shared__ float wx[TT];
    __shared__ int sflag;
    const int b = blockIdx.x;
    const int d = threadIdx.x;          // 0..511
    if (d == 0) sflag = *flag_ws;
    __syncthreads();
    const int f32m = sflag;

    if (d < TT)
        wx[d] = f32m ? ((const float*)attn_wv)[2 * HH + d]
                     : bf2f(((const unsigned short*)attn_wv)[2 * HH + d]);
    __syncthreads();

    const size_t xb = (size_t)b * TT * DD;
    float s = 0.f;
    for (int t = 0; t < TT; ++t) {
        size_t ix = xb + (size_t)t * DD + d;
        float xval = f32m ? ((const float*)xv)[ix] : bf2f(((const unsigned short*)xv)[ix]);
        s += xval * wx[t];
    }

    red[d] = s; __syncthreads();
    for (int off = 256; off > 0; off >>= 1) {
        if (d < off) red[d] = fmaxf(red[d], red[d + off]);
        __syncthreads();
    }
    const float m = red[0]; __syncthreads();
    const float e = expf(s - m);
    red[d] = e; __syncthreads();
    for (int off = 256; off > 0; off >>= 1) {
        if (d < off) red[d] += red[d + off];
        __syncthreads();
    }
    const float a = e / red[0];

    for (int t = 0; t < TT; ++t) {
        size_t ix = xb + (size_t)t * DD + d;
        float xval = f32m ? ((const float*)xv)[ix] : bf2f(((const unsigned short*)xv)[ix]);
        float v = a * xval;
        const unsigned short vb = f2bf(v);
        if (f32m) ((float*)outv)[ix] = v;
        else      ((unsigned short*)outv)[ix] = vb;
        x_bf[ix] = vb;                  // coalesced 1KB/row bf16 copy
    }
}

// ---------------------------------------------------------------------------
// Kernel 2: persistent 3-layer LSTM wavefront.
// Coherence design (proven R0-R5): h_ws written via agent-scope relaxed
// atomic stores (sc1, LLC write-through), read via global_load_dwordx4
// sc0 sc1, deduped to 3 slices / 24 loads per wave per tick;
// writeback-free arrival; SPSC group barriers; blk-derived roles
// (R5 verified the physical XCD mapping matches blk&7).
//
// NEW this round: VECTOR bf16 A-LOADS (TA-pressure theory).
//   R3's gain was ~240 cyc per REMOVED memory instruction -- the
//   signature of the per-CU texture-addresser (~1 line-request/cyc),
//   invisible in VALUBusy/MfmaUtil/FETCH. The f32-mode layer-0 A-load
//   issued 128 scalar 4B loads/wave/tick with lanes 260KB apart
//   (~32 lines/inst): ~16k TA-cyc/CU/tick = most of the ~25us residue
//   that survived every sync-path change. attn now emits a bf16 copy
//   x_bf; layer 0 loads it as short8 (16 insts/wave, 64x fewer TA
//   requests on this path, f2bf VALU chains deleted). Numerics
//   unchanged: the A operand was already bf16-rounded before MFMA.
// ---------------------------------------------------------------------------
__global__ __launch_bounds__(256, 1) void lstm_kernel(
    void* __restrict__ outv,                  // d_out: write out1
    const unsigned short* __restrict__ W_ih_o,
    const unsigned short* __restrict__ W_hh_o,
    const unsigned short* __restrict__ wih_bf,
    const unsigned short* __restrict__ whh_bf,
    const float* __restrict__ bsum,           // [3][GG]
    unsigned short* __restrict__ h_ws,        // [3][2][B][HH] bf16 parity dbuf
    unsigned* __restrict__ bar,               // 512 slots x 2KB (arr, wake)
    const unsigned short* __restrict__ x_bf,  // [B][TT][DD] bf16 A operand
    const int* __restrict__ flag_ws)
{
    __shared__ float g_lds[16 * 16 * 33];     // [(q*4+g)*16+hid]*33 + batch
    __shared__ int sflag;
    __shared__ int s_dead;

    const int tid = threadIdx.x;
    if (tid == 0) { sflag = *flag_ws; s_dead = 0; }
    __syncthreads();
    const int f32m = sflag;

    const unsigned short* WiB = f32m ? wih_bf : W_ih_o;
    const unsigned short* WhB = f32m ? whh_bf : W_hh_o;

    const int lane   = tid & 63;
    const int wv     = tid >> 6;              // wave id 0..3 = K-quarter
    const int m_lane = lane & 15;
    const int kq     = lane >> 4;

    const int blk = blockIdx.x;
    const int hi  = (blk & 7) * 4 + ((blk >> 3) & 3);  // hidden slice 0..31
    const int bi  = blk >> 5;                           // batch tile 0..7
    const int hid0 = hi * 16;
    const int b0   = bi * 32;
    const int leader = (hi == 0);             // block 32*bi leads group bi

    // SPSC barrier slots (2KB apart; 1 writer + 1 reader each)
    char* barc = (char*)bar;
    unsigned* arr_my  = (unsigned*)(barc + (size_t)(bi * 32 + hi) * BARSLOT);
    unsigned* wake_my = (unsigned*)(barc + (size_t)(256 + bi * 32 + hi) * BARSLOT);
    // leader wave0: lane j polls arrival slot j (lanes>=32 mirror slot 31)
    unsigned* poll_slot = (unsigned*)(barc +
        (size_t)(bi * 32 + (tid < 32 ? tid : 31)) * BARSLOT);
    unsigned* wake_slot = (unsigned*)(barc +
        (size_t)(256 + bi * 32 + (tid < 32 ? tid : 31)) * BARSLOT);

    // epilogue ownership: thread -> (batch bl, hid pair hp)
    const int ep_bl = tid >> 3;               // 0..31
    const int ep_hp = tid & 7;                // hid pair, hids {2hp, 2hp+1}

    float c_reg[3][2];
#pragma unroll
    for (int l = 0; l < 3; ++l) { c_reg[l][0] = 0.f; c_reg[l][1] = 0.f; }

    for (int k = 0; k < TT + 2; ++k) {
        // ---- tick-start burst: 24 coherent 16B loads (3 unique slices) ----
        // pfb[j] = h_j[k-1-j] (parity (k-j-1)&1). Serves BOTH layer j's
        // hprev and layer j+1's hsrc. Load iff 0 <= k-j <= TT. (-1)&1==1:
        // the t=-1 read hits the memset-zeroed parity-1 buffer.
        short8 pfb[3][4][2];
#pragma unroll
        for (int j = 0; j < 3; ++j) {
            const int kj = k - j;
            if (kj < 0 || kj > TT) continue;  // uniform across wgs & threads
            const unsigned short* hb =
                h_ws + ((size_t)j * 2 + ((kj - 1) & 1)) * BATCH * HH;
#pragma unroll
            for (int kk = 0; kk < 4; ++kk) {
                const int k0 = (wv * 4 + kk) * 32 + kq * 8;
                pfb[j][kk][0] = load_h16(hb + (size_t)(b0 + m_lane) * HH + k0);
                pfb[j][kk][1] = load_h16(hb + (size_t)(b0 + 16 + m_lane) * HH + k0);
            }
        }
        // drain the untracked asm loads ONCE; fence the scheduler so no
        // consumer is hoisted above the wait (rule 18).
        asm volatile("s_waitcnt vmcnt(0)" ::: "memory");
        __builtin_amdgcn_sched_barrier(0);

        // --------------------------- compute ----------------------------
#pragma unroll
        for (int l = 0; l < 3; ++l) {
            const int t = k - l;
            if (t < 0 || t >= TT) continue;   // uniform across wgs & threads

            const unsigned short* Wi = WiB + (size_t)l * GG * DD;
            const unsigned short* Wh = WhB + (size_t)l * GG * DD;

            floatx4 acc[2][4];
#pragma unroll
            for (int mt = 0; mt < 2; ++mt)
#pragma unroll
                for (int g = 0; g < 4; ++g) {
                    floatx4 z = {0.f, 0.f, 0.f, 0.f};
                    acc[mt][g] = z;
                }

#pragma unroll
            for (int kk = 0; kk < 4; ++kk) {
                const int k0 = (wv * 4 + kk) * 32 + kq * 8;
                short8 a0, a1;
                if (l == 0) {
                    a0 = *(const short8*)(x_bf + ((size_t)(b0 + m_lane) * TT + t) * DD + k0);
                    a1 = *(const short8*)(x_bf + ((size_t)(b0 + 16 + m_lane) * TT + t) * DD + k0);
                } else {
                    a0 = pfb[l - 1][kk][0];   // hsrc == hprev of layer l-1
                    a1 = pfb[l - 1][kk][1];
                }
#pragma unroll
                for (int g = 0; g < 4; ++g) {
                    short8 bfr = *(const short8*)(Wi + (size_t)(g * HH + hid0 + m_lane) * DD + k0);
                    acc[0][g] = __builtin_amdgcn_mfma_f32_16x16x32_bf16(a0, bfr, acc[0][g], 0, 0, 0);
                    acc[1][g] = __builtin_amdgcn_mfma_f32_16x16x32_bf16(a1, bfr, acc[1][g], 0, 0, 0);
                }
                short8 h0f = pfb[l][kk][0];
                short8 h1f = pfb[l][kk][1];
#pragma unroll
                for (int g = 0; g < 4; ++g) {
                    short8 bfr = *(const short8*)(Wh + (size_t)(g * HH + hid0 + m_lane) * DD + k0);
                    acc[0][g] = __builtin_amdgcn_mfma_f32_16x16x32_bf16(h0f, bfr, acc[0][g], 0, 0, 0);
                    acc[1][g] = __builtin_amdgcn_mfma_f32_16x16x32_bf16(h1f, bfr, acc[1][g], 0, 0, 0);
                }
            }

            // combine 4 waves' K-partials in LDS
            __syncthreads();
#pragma unroll
            for (int mt = 0; mt < 2; ++mt)
#pragma unroll
                for (int g = 0; g < 4; ++g)
#pragma unroll
                    for (int r = 0; r < 4; ++r)
                        g_lds[((wv * 4 + g) * 16 + m_lane) * 33 + mt * 16 + kq * 4 + r]
                            = acc[mt][g][r];
            __syncthreads();

            // epilogue: each thread owns (bl, hid-pair) -> packed u32 h-store
            {
                float hout[2];
#pragma unroll
                for (int dlt = 0; dlt < 2; ++dlt) {
                    const int hid = 2 * ep_hp + dlt;
                    float gv[4];
#pragma unroll
                    for (int g = 0; g < 4; ++g) {
                        float sum = 0.f;
#pragma unroll
                        for (int q = 0; q < 4; ++q)
                            sum += g_lds[((q * 4 + g) * 16 + hid) * 33 + ep_bl];
                        sum += bsum[l * GG + g * HH + hid0 + hid];
                        gv[g] = sum;
                    }
                    const float ig = 1.f / (1.f + expf(-gv[0]));
                    const float fg = 1.f / (1.f + expf(-gv[1]));
                    const float gg = tanhf(gv[2]);
                    const float og = 1.f / (1.f + expf(-gv[3]));
                    const float cnew = fg * c_reg[l][dlt] + ig * gg;
                    c_reg[l][dlt] = cnew;
                    hout[dlt] = og * tanhf(cnew);
                }
                const int bgl  = b0 + ep_bl;
                const int hidg = hid0 + 2 * ep_hp;
                const unsigned hpk = (unsigned)f2bf(hout[0])
                                   | ((unsigned)f2bf(hout[1]) << 16);
                __hip_atomic_store(
                    (unsigned*)(h_ws + (((size_t)l * 2 + (t & 1)) * BATCH + bgl) * HH + hidg),
                    hpk, __ATOMIC_RELAXED, __HIP_MEMORY_SCOPE_AGENT);
                if (l == 2) {
                    const size_t ox = OUT0_ELEMS + ((size_t)bgl * TT + t) * HH + hidg;
                    if (f32m) {
                        ((float*)outv)[ox]     = hout[0];
                        ((float*)outv)[ox + 1] = hout[1];
                    } else {
                        *(unsigned*)((unsigned short*)outv + ox) = hpk;
                    }
                }
            }
        }

        if (k < TT + 1) {
            // __syncthreads drains every wave's vmcnt (compiler emits
            // s_waitcnt vmcnt(0) lgkmcnt(0) before s_barrier) -> all h
            // stores of this block are LLC-visible before the arrival.
            __syncthreads();
            if (!s_dead) {
                if (tid == 0) {
                    asm volatile("s_waitcnt vmcnt(0)" ::: "memory");
                    __hip_atomic_store(arr_my, (unsigned)(k + 1),
                                       __ATOMIC_RELAXED, __HIP_MEMORY_SCOPE_AGENT);
                }
                if (leader) {
                    if (tid < 64) {
                        // lane-parallel poll of the 32 arrival slots:
                        // one LLC round-trip per poll round.
                        int spins = 0;
                        for (;;) {
                            unsigned v = __hip_atomic_load(poll_slot,
                                __ATOMIC_RELAXED, __HIP_MEMORY_SCOPE_AGENT);
                            if (__all(v > (unsigned)k)) break;
                            __builtin_amdgcn_s_sleep(4);
                            if (++spins > 2000000) {
                                if (tid == 0) s_dead = 1;
                                break;
                            }
                        }
                        if (tid < 32)
                            __hip_atomic_store(wake_slot, (unsigned)(k + 1),
                                __ATOMIC_RELAXED, __HIP_MEMORY_SCOPE_AGENT);
                    }
                } else if (tid == 0) {
                    int spins = 0;
                    while (__hip_atomic_load(wake_my, __ATOMIC_RELAXED,
                                             __HIP_MEMORY_SCOPE_AGENT)
                           <= (unsigned)k) {
                        __builtin_amdgcn_s_sleep(4);
                        if (++spins > 2000000) { s_dead = 1; break; }
                    }
                }
            }
            __syncthreads();
        }
    }
}

// ---------------------------------------------------------------------------
// workspace layout (bytes)
// ---------------------------------------------------------------------------
#define WIH_OFF  ((size_t)0)
#define WIH_SZ   ((size_t)3 * GG * DD * 2)          // 6,291,456
#define WHH_OFF  (WIH_OFF + WIH_SZ)
#define WHH_SZ   WIH_SZ
#define BSUM_OFF (WHH_OFF + WHH_SZ)
#define BSUM_SZ  ((size_t)3 * GG * 4)               // 24,576
#define H_OFF    (BSUM_OFF + BSUM_SZ)
#define H_SZ     ((size_t)3 * 2 * BATCH * HH * 2)   // 1,572,864
#define BAR_OFF  (H_OFF + H_SZ)                     // 512 slots x 2KB
#define BAR_SZ   ((size_t)512 * BARSLOT)            // 1,048,576
#define FLAG_OFF (BAR_OFF + BAR_SZ)
#define XBF_OFF  (FLAG_OFF + 256)
#define XBF_SZ   (OUT0_ELEMS * 2)                   // 33,292,288
#define WS_NEED  (XBF_OFF + XBF_SZ)                 // ~48.6 MB

extern "C" void kernel_launch(void* const* d_in, const int* in_sizes, int n_in,
                              void* d_out, int out_size, void* d_ws, size_t ws_size,
                              hipStream_t stream) {
    (void)in_sizes; (void)n_in; (void)out_size;

    const void* x      = d_in[0];
    const void* W_ih   = d_in[1];
    const void* W_hh   = d_in[2];
    const void* b_ih   = d_in[3];
    const void* b_hh   = d_in[4];
    const void* attn_w = d_in[5];
    // d_in[6] (attn_b) cancels in the softmax — unused.

    char* ws = (char*)d_ws;
    unsigned short* wih_bf = (unsigned short*)(ws + WIH_OFF);
    unsigned short* whh_bf = (unsigned short*)(ws + WHH_OFF);
    float*          bsum   = (float*)(ws + BSUM_OFF);
    unsigned short* h_ws   = (unsigned short*)(ws + H_OFF);
    unsigned*       bar    = (unsigned*)(ws + BAR_OFF);
    int*            flagp  = (int*)(ws + FLAG_OFF);
    unsigned short* x_bf   = (unsigned short*)(ws + XBF_OFF);

    if (ws_size < WS_NEED) return;

    // zero h (both parities) + barrier slots + flag every call
    hipMemsetAsync(ws + H_OFF, 0, H_SZ + BAR_SZ + 256, stream);

    prep_kernel<<<dim3(1024), dim3(256), 0, stream>>>(
        W_ih, W_hh, b_ih, b_hh, (const unsigned short*)x,
        wih_bf, whh_bf, bsum, flagp);

    attn_kernel<<<dim3(BATCH), dim3(512), 0, stream>>>(
        x, attn_w, d_out, x_bf, flagp);

    lstm_kernel<<<dim3(NWG), dim3(NTHR), 0, stream>>>(
        d_out, (const unsigned short*)W_ih, (const unsigned short*)W_hh,
        wih_bf, whh_bf, bsum, h_ws, bar, x_bf, flagp);
}